// Round 5
// baseline (539.565 us; speedup 1.0000x reference)
//
#include <hip/hip_runtime.h>
#include <cstddef>

#define NN 262144
#define F_DIM 128
#define G_SEG 4096
#define H_DIM 512
#define SEG_SZ 64
#define KDIM 1024   // 2H
#define NDIM 2048   // 4H

typedef unsigned short u16;
typedef __attribute__((ext_vector_type(8))) __bf16 bf16x8;
typedef __attribute__((ext_vector_type(4))) float f32x4;

__device__ __forceinline__ float hsig(float x) {
    return fminf(fmaxf(0.2f * x + 0.5f, 0.0f), 1.0f);
}

// float -> bf16 bits, round-nearest-even
__device__ __forceinline__ u16 f2bf(float x) {
    union { float f; unsigned u; } v; v.f = x;
    unsigned r = (v.u + 0x7fffu + ((v.u >> 16) & 1u)) >> 16;
    return (u16)r;
}

// m_weight (F,H) -> mwT (H,F)
__global__ void k_transpose(const float* __restrict__ mw, float* __restrict__ mwT) {
    int id = blockIdx.x * blockDim.x + threadIdx.x;
    if (id < F_DIM * H_DIM) {
        int f = id / H_DIM, j = id % H_DIM;
        mwT[j * F_DIM + f] = mw[id];
    }
}

// recurrent_kernel (K=1024, N=2048) fp32 -> B^T bf16 (N rows, K cols)
__global__ __launch_bounds__(256) void k_bt(const float* __restrict__ rk, u16* __restrict__ bt) {
    __shared__ u16 t[64][65];
    int tid = threadIdx.x;
    int n0 = blockIdx.x * 64, k0 = blockIdx.y * 64;
    for (int i = tid; i < 64 * 64; i += 256) {
        int r = i >> 6, cc = i & 63;
        t[r][cc] = f2bf(rk[(size_t)(k0 + r) * NDIM + n0 + cc]);
    }
    __syncthreads();
    for (int i = tid; i < 64 * 64; i += 256) {
        int n = i >> 6, k = i & 63;
        bt[(size_t)(n0 + n) * KDIM + k0 + k] = t[k][n];
    }
}

// z = qstar_bf16 @ RK  via MFMA.  A: [4096][1024] bf16, BT: [2048][1024] bf16, C: [4096][2048] f32
#define GBM 128
#define GBN 128
#define GBK 32
__global__ __launch_bounds__(256) void k_gemm_mfma(const u16* __restrict__ A,
                                                   const u16* __restrict__ BT,
                                                   float* __restrict__ C) {
    __shared__ u16 sA[GBM * GBK];   // [row][kchunk] 16B chunks, source-side XOR swizzle
    __shared__ u16 sB[GBN * GBK];
    int tid = threadIdx.x;
    int lane = tid & 63, wv = tid >> 6;
    int wm = (wv >> 1) * 64, wn = (wv & 1) * 64;
    int bm = blockIdx.y * GBM, bn = blockIdx.x * GBN;
    const u16* Ab = A + (size_t)bm * KDIM;
    const u16* Bb = BT + (size_t)bn * KDIM;
    int r16 = lane & 15, kc = lane >> 4;
    f32x4 acc[4][4] = {};

    for (int k0 = 0; k0 < KDIM; k0 += GBK) {
#pragma unroll
        for (int i = 0; i < 2; ++i) {
            int ch = i * 256 + tid;            // 0..511
            int row = ch >> 2, cc = ch & 3;
            int ccs = cc ^ ((row >> 1) & 3);
            __builtin_amdgcn_global_load_lds(
                (const __attribute__((address_space(1))) void*)(Ab + (size_t)row * KDIM + k0 + ccs * 8),
                (__attribute__((address_space(3))) void*)(&sA[ch * 8]), 16, 0, 0);
            __builtin_amdgcn_global_load_lds(
                (const __attribute__((address_space(1))) void*)(Bb + (size_t)row * KDIM + k0 + ccs * 8),
                (__attribute__((address_space(3))) void*)(&sB[ch * 8]), 16, 0, 0);
        }
        __syncthreads();
        bf16x8 af[4], bfr[4];
#pragma unroll
        for (int mi = 0; mi < 4; ++mi) {
            int row = wm + mi * 16 + r16;
            int off = row * GBK + ((kc ^ ((row >> 1) & 3)) * 8);
            af[mi] = *reinterpret_cast<const bf16x8*>(&sA[off]);
        }
#pragma unroll
        for (int ni = 0; ni < 4; ++ni) {
            int row = wn + ni * 16 + r16;
            int off = row * GBK + ((kc ^ ((row >> 1) & 3)) * 8);
            bfr[ni] = *reinterpret_cast<const bf16x8*>(&sB[off]);
        }
#pragma unroll
        for (int mi = 0; mi < 4; ++mi)
#pragma unroll
            for (int ni = 0; ni < 4; ++ni)
                acc[mi][ni] = __builtin_amdgcn_mfma_f32_16x16x32_bf16(af[mi], bfr[ni], acc[mi][ni], 0, 0, 0);
        __syncthreads();
    }
#pragma unroll
    for (int mi = 0; mi < 4; ++mi)
#pragma unroll
        for (int ni = 0; ni < 4; ++ni)
#pragma unroll
            for (int r = 0; r < 4; ++r) {
                int row = bm + wm + mi * 16 + kc * 4 + r;
                int col = bn + wn + ni * 16 + r16;
                C[(size_t)row * NDIM + col] = acc[mi][ni][r];
            }
}

// gates: c = hs(zf)*c + hs(zi)*tanh(zc); h = hs(zo)*tanh(c); h -> out[:, :H] and qsb bf16
// t=0 path (z==nullptr): c_prev == 0 is implied, no c read (no memset needed).
__global__ void k_gates(const float* __restrict__ z, const float* __restrict__ rb,
                        float* __restrict__ c, float* __restrict__ out,
                        u16* __restrict__ qsb) {
    int id = blockIdx.x * blockDim.x + threadIdx.x;  // over G*H
    int g = id >> 9, j = id & 511;
    float zi = rb[j], zf = rb[H_DIM + j], zc = rb[2 * H_DIM + j], zo = rb[3 * H_DIM + j];
    float cn;
    if (z) {
        const float* zr = z + (size_t)g * 4 * H_DIM;
        zi += zr[j]; zf += zr[H_DIM + j]; zc += zr[2 * H_DIM + j]; zo += zr[3 * H_DIM + j];
        cn = hsig(zf) * c[id] + hsig(zi) * tanhf(zc);
    } else {
        cn = hsig(zi) * tanhf(zc);
    }
    c[id] = cn;
    float h = hsig(zo) * tanhf(cn);
    out[(size_t)g * 1024 + j] = h;
    qsb[(size_t)g * 1024 + j] = f2bf(h);
}

// Tiled: W[g,f] = sum_j h[g,j]*mwT[j,f]; bsum[g] = sum_j h[g,j]*mb[j]
// 16 segments per block; mwT staged in LDS chunks (kills the 1 GB/iter L2 re-read).
#define WSEG 16
#define WBK 128
__global__ __launch_bounds__(256) void k_W(const float* __restrict__ out,
                                           const float* __restrict__ mwT,
                                           const float* __restrict__ mb,
                                           float* __restrict__ W,
                                           float* __restrict__ bsum) {
    __shared__ float smw[WBK][F_DIM];   // 64 KB
    __shared__ float shl[WSEG][WBK];    // 8 KB
    int g0 = blockIdx.x * WSEG;
    int t = threadIdx.x;
    int f = t & 127, sh = t >> 7;
    float acc[8] = {};
    for (int k0 = 0; k0 < H_DIM; k0 += WBK) {
        for (int i = t; i < WBK * 32; i += 256) {
            int r = i >> 5, c4 = (i & 31) << 2;
            *reinterpret_cast<float4*>(&smw[r][c4]) =
                *reinterpret_cast<const float4*>(&mwT[(size_t)(k0 + r) * F_DIM + c4]);
        }
        for (int i = t; i < WSEG * WBK / 4; i += 256) {
            int s = i >> 5, c4 = (i & 31) << 2;
            *reinterpret_cast<float4*>(&shl[s][c4]) =
                *reinterpret_cast<const float4*>(&out[(size_t)(g0 + s) * 1024 + k0 + c4]);
        }
        __syncthreads();
        for (int kk = 0; kk < WBK; ++kk) {
            float w = smw[kk][f];
#pragma unroll
            for (int s = 0; s < 8; ++s)
                acc[s] = fmaf(shl[sh + 2 * s][kk], w, acc[s]);
        }
        __syncthreads();
    }
#pragma unroll
    for (int s = 0; s < 8; ++s)
        W[(size_t)(g0 + sh + 2 * s) * F_DIM + f] = acc[s];
    // bsum: wave wv handles segs wv, wv+4, wv+8, wv+12 (h re-read from L2-hot out)
    int wv = t >> 6, lane = t & 63;
    for (int si = 0; si < 4; ++si) {
        int g = g0 + wv + si * 4;
        float b = 0.f;
        for (int j = lane; j < H_DIM; j += 64)
            b = fmaf(out[(size_t)g * 1024 + j], mb[j], b);
#pragma unroll
        for (int off = 32; off >= 1; off >>= 1) b += __shfl_xor(b, off);
        if (lane == 0) bsum[g] = b;
    }
}

// per-segment attn: 128 threads (2 waves) per segment.
// e-dot split across waves; fsum one col/thread. 8 waves/CU (was 4).
__global__ __launch_bounds__(128) void k_attn(const float* __restrict__ feats,
                                              const float* __restrict__ wts,
                                              const float* __restrict__ W,
                                              const float* __restrict__ bsum,
                                              float* __restrict__ fsum) {
    int g = blockIdx.x;
    int t = threadIdx.x;           // 0..127
    __shared__ float fl[SEG_SZ * 129];
    __shared__ float Wl[F_DIM];
    __shared__ float ep[2][SEG_SZ];
    __shared__ float al[SEG_SZ];
    const float4* f4 = reinterpret_cast<const float4*>(feats + (size_t)g * SEG_SZ * F_DIM);
    for (int i = t; i < SEG_SZ * F_DIM / 4; i += 128) {
        float4 v = f4[i];
        int n = i >> 5;
        int f = (i & 31) << 2;
        float* p = &fl[n * 129 + f];
        p[0] = v.x; p[1] = v.y; p[2] = v.z; p[3] = v.w;
    }
    Wl[t] = W[g * F_DIM + t];
    __syncthreads();
    int row = t & 63, half = t >> 6;
    const float* fr = &fl[row * 129 + half * 64];
    const float* wr = &Wl[half * 64];
    float e = 0.f;
#pragma unroll
    for (int f = 0; f < 64; ++f) e = fmaf(fr[f], wr[f], e);
    ep[half][row] = e;
    __syncthreads();
    if (t < 64) {
        float ee = ep[0][t] + ep[1][t] + bsum[g];
        float mx = ee;
#pragma unroll
        for (int off = 32; off >= 1; off >>= 1) mx = fmaxf(mx, __shfl_xor(mx, off));
        float ex = expf(ee - mx) * wts[g * SEG_SZ + t];
        float s = ex;
#pragma unroll
        for (int off = 32; off >= 1; off >>= 1) s += __shfl_xor(s, off);
        al[t] = ex / s;
    }
    __syncthreads();
    float a0 = 0.f;
#pragma unroll
    for (int n = 0; n < SEG_SZ; ++n)
        a0 = fmaf(al[n], fl[n * 129 + t], a0);
    fsum[g * F_DIM + t] = a0;
}

// r[g] = fsum[g] @ mw + mb -> out[:, H:2H] and qsb bf16
#define RGB 8
__global__ __launch_bounds__(512) void k_r(const float* __restrict__ fsum,
                                           const float* __restrict__ mw,
                                           const float* __restrict__ mb,
                                           float* __restrict__ out,
                                           u16* __restrict__ qsb) {
    int g0 = blockIdx.x * RGB;
    int tid = threadIdx.x;
    __shared__ float fs[RGB][F_DIM];
    for (int i = tid; i < RGB * F_DIM; i += 512)
        fs[i >> 7][i & 127] = fsum[g0 * F_DIM + i];
    __syncthreads();
    float acc[RGB] = {};
    for (int f = 0; f < F_DIM; ++f) {
        float w = mw[f * H_DIM + tid];
#pragma unroll
        for (int s = 0; s < RGB; ++s) acc[s] = fmaf(fs[s][f], w, acc[s]);
    }
    float bias = mb[tid];
#pragma unroll
    for (int s = 0; s < RGB; ++s) {
        float v = acc[s] + bias;
        out[(size_t)(g0 + s) * 1024 + H_DIM + tid] = v;
        qsb[(size_t)(g0 + s) * 1024 + H_DIM + tid] = f2bf(v);
    }
}

extern "C" void kernel_launch(void* const* d_in, const int* in_sizes, int n_in,
                              void* d_out, int out_size, void* d_ws, size_t ws_size,
                              hipStream_t stream) {
    const float* feats = (const float*)d_in[0];
    const float* wts   = (const float*)d_in[1];
    // d_in[2] = index: structurally n/64 (sorted, 64 nodes/segment) — not needed
    const float* mw    = (const float*)d_in[3];
    const float* mb    = (const float*)d_in[4];
    const float* rk    = (const float*)d_in[5];
    const float* rb    = (const float*)d_in[6];
    float* out = (float*)d_out;

    float* z    = (float*)d_ws;                       // G*4H   = 8M floats
    float* c    = z + (size_t)G_SEG * 4 * H_DIM;      // G*H    = 2M
    float* W    = c + (size_t)G_SEG * H_DIM;          // G*F    = 512K
    float* bs   = W + (size_t)G_SEG * F_DIM;          // G
    float* fsum = bs + G_SEG;                         // G*F    = 512K
    float* mwT  = fsum + (size_t)G_SEG * F_DIM;       // H*F    = 64K
    u16*   qsb  = (u16*)(mwT + H_DIM * F_DIM);        // G*2H bf16 = 8 MB
    u16*   bt   = qsb + (size_t)G_SEG * KDIM;         // N*K bf16  = 4 MB

    k_transpose<<<(F_DIM * H_DIM + 255) / 256, 256, 0, stream>>>(mw, mwT);
    k_bt<<<dim3(NDIM / 64, KDIM / 64), 256, 0, stream>>>(rk, bt);

    for (int t = 0; t < 3; ++t) {
        if (t > 0) {
            k_gemm_mfma<<<dim3(NDIM / GBN, G_SEG / GBM), 256, 0, stream>>>(qsb, bt, z);
            k_gates<<<(G_SEG * H_DIM) / 256, 256, 0, stream>>>(z, rb, c, out, qsb);
        } else {
            k_gates<<<(G_SEG * H_DIM) / 256, 256, 0, stream>>>(nullptr, rb, c, out, qsb);
        }
        k_W<<<G_SEG / WSEG, 256, 0, stream>>>(out, mwT, mb, W, bs);
        k_attn<<<G_SEG, 128, 0, stream>>>(feats, wts, W, bs, fsum);
        k_r<<<G_SEG / RGB, 512, 0, stream>>>(fsum, mw, mb, out, qsb);
    }
}

// Round 6
// 521.292 us; speedup vs baseline: 1.0351x; 1.0351x over previous
//
#include <hip/hip_runtime.h>
#include <cstddef>

#define NN 262144
#define F_DIM 128
#define G_SEG 4096
#define H_DIM 512
#define SEG_SZ 64
#define KDIM 1024   // 2H
#define NDIM 2048   // 4H

typedef unsigned short u16;
typedef __attribute__((ext_vector_type(8))) __bf16 bf16x8;
typedef __attribute__((ext_vector_type(4))) float f32x4;

__device__ __forceinline__ float hsig(float x) {
    return fminf(fmaxf(0.2f * x + 0.5f, 0.0f), 1.0f);
}

// float -> bf16 bits, round-nearest-even
__device__ __forceinline__ u16 f2bf(float x) {
    union { float f; unsigned u; } v; v.f = x;
    unsigned r = (v.u + 0x7fffu + ((v.u >> 16) & 1u)) >> 16;
    return (u16)r;
}

// m_weight (F,H) -> mwT (H,F)
__global__ void k_transpose(const float* __restrict__ mw, float* __restrict__ mwT) {
    int id = blockIdx.x * blockDim.x + threadIdx.x;
    if (id < F_DIM * H_DIM) {
        int f = id / H_DIM, j = id % H_DIM;
        mwT[j * F_DIM + f] = mw[id];
    }
}

// recurrent_kernel (K=1024, N=2048) fp32 -> permuted B^T bf16.
// Row rn of btg = original column n, with rn = (jj>>5)*128 + q*32 + (jj&31),
// where q = n>>9 (gate), jj = n&511 (within-gate col). This makes GEMM block bn
// own all 4 gates of j-strip [bn*32, bn*32+32).
__global__ __launch_bounds__(256) void k_bt(const float* __restrict__ rk, u16* __restrict__ btg) {
    __shared__ u16 t[64][65];
    int tid = threadIdx.x;
    int n0 = blockIdx.x * 64, k0 = blockIdx.y * 64;
    for (int i = tid; i < 64 * 64; i += 256) {
        int r = i >> 6, cc = i & 63;
        t[r][cc] = f2bf(rk[(size_t)(k0 + r) * NDIM + n0 + cc]);
    }
    __syncthreads();
    for (int i = tid; i < 64 * 64; i += 256) {
        int n = i >> 6, k = i & 63;
        int nc = n0 + n;
        int q = nc >> 9, jj = nc & 511;
        int rn = (jj >> 5) * 128 + q * 32 + (jj & 31);
        btg[(size_t)rn * KDIM + k0 + k] = t[k][n];
    }
}

// Fused z-GEMM + LSTM gates.  A = qsb [4096][1024] bf16, BTG as above.
// Block (bx, by): rows by*128.., j-strip bx*32... Wave wv owns 32 rows x 128 cols.
// Lane layout per mfma 16x16x32: col=lane&15 (local n), row=(lane>>4)*4+reg.
// nl = ni*16 + r16 -> gate q = ni>>1, j = j0 + (ni&1)*16 + r16.
#define GBM 128
#define GBK 32
__global__ __launch_bounds__(256) void k_gemm_gates(const u16* __restrict__ A,
                                                    const u16* __restrict__ BTG,
                                                    const float* __restrict__ rb,
                                                    float* __restrict__ c,
                                                    float* __restrict__ out,
                                                    u16* __restrict__ qsb) {
    __shared__ u16 sA[GBM * GBK];
    __shared__ u16 sB[GBM * GBK];
    int tid = threadIdx.x;
    int lane = tid & 63, wv = tid >> 6;
    int wm = wv * 32;
    int bm = blockIdx.y * GBM;
    int j0 = blockIdx.x * 32;
    const u16* Ab = A + (size_t)bm * KDIM;
    const u16* Bb = BTG + (size_t)(blockIdx.x * 128) * KDIM;
    int r16 = lane & 15, kc = lane >> 4;
    f32x4 acc[2][8] = {};

    for (int k0 = 0; k0 < KDIM; k0 += GBK) {
#pragma unroll
        for (int i = 0; i < 2; ++i) {
            int ch = i * 256 + tid;            // 0..511
            int row = ch >> 2, cc = ch & 3;
            int ccs = cc ^ ((row >> 1) & 3);
            __builtin_amdgcn_global_load_lds(
                (const __attribute__((address_space(1))) void*)(Ab + (size_t)row * KDIM + k0 + ccs * 8),
                (__attribute__((address_space(3))) void*)(&sA[ch * 8]), 16, 0, 0);
            __builtin_amdgcn_global_load_lds(
                (const __attribute__((address_space(1))) void*)(Bb + (size_t)row * KDIM + k0 + ccs * 8),
                (__attribute__((address_space(3))) void*)(&sB[ch * 8]), 16, 0, 0);
        }
        __syncthreads();
        bf16x8 af[2], bfr[8];
#pragma unroll
        for (int mi = 0; mi < 2; ++mi) {
            int row = wm + mi * 16 + r16;
            int off = row * GBK + ((kc ^ ((row >> 1) & 3)) * 8);
            af[mi] = *reinterpret_cast<const bf16x8*>(&sA[off]);
        }
#pragma unroll
        for (int ni = 0; ni < 8; ++ni) {
            int row = ni * 16 + r16;
            int off = row * GBK + ((kc ^ ((row >> 1) & 3)) * 8);
            bfr[ni] = *reinterpret_cast<const bf16x8*>(&sB[off]);
        }
#pragma unroll
        for (int mi = 0; mi < 2; ++mi)
#pragma unroll
            for (int ni = 0; ni < 8; ++ni)
                acc[mi][ni] = __builtin_amdgcn_mfma_f32_16x16x32_bf16(af[mi], bfr[ni], acc[mi][ni], 0, 0, 0);
        __syncthreads();
    }

    // epilogue: LSTM cell update, all 4 gates resident in this lane
    float rbv[4][2];
#pragma unroll
    for (int q = 0; q < 4; ++q) {
        rbv[q][0] = rb[q * H_DIM + j0 + r16];
        rbv[q][1] = rb[q * H_DIM + j0 + 16 + r16];
    }
#pragma unroll
    for (int mi = 0; mi < 2; ++mi)
#pragma unroll
        for (int r = 0; r < 4; ++r) {
            int row = bm + wm + mi * 16 + kc * 4 + r;
#pragma unroll
            for (int jj = 0; jj < 2; ++jj) {
                int j = j0 + jj * 16 + r16;
                float zi = acc[mi][0 + jj][r] + rbv[0][jj];
                float zf = acc[mi][2 + jj][r] + rbv[1][jj];
                float zc = acc[mi][4 + jj][r] + rbv[2][jj];
                float zo = acc[mi][6 + jj][r] + rbv[3][jj];
                size_t ci = (size_t)row * H_DIM + j;
                float cn = hsig(zf) * c[ci] + hsig(zi) * tanhf(zc);
                c[ci] = cn;
                float h = hsig(zo) * tanhf(cn);
                out[(size_t)row * 1024 + j] = h;
                qsb[(size_t)row * 1024 + j] = f2bf(h);
            }
        }
}

// t=0 gates only: z == rb broadcast, c_prev == 0 (no read, no memset needed)
__global__ void k_gates0(const float* __restrict__ rb,
                         float* __restrict__ c, float* __restrict__ out,
                         u16* __restrict__ qsb) {
    int id = blockIdx.x * blockDim.x + threadIdx.x;  // over G*H
    int g = id >> 9, j = id & 511;
    float zi = rb[j], zc = rb[2 * H_DIM + j], zo = rb[3 * H_DIM + j];
    float cn = hsig(zi) * tanhf(zc);
    c[id] = cn;
    float h = hsig(zo) * tanhf(cn);
    out[(size_t)g * 1024 + j] = h;
    qsb[(size_t)g * 1024 + j] = f2bf(h);
}

// Tiled: W[g,f] = sum_j h[g,j]*mwT[j,f]; bsum[g] = sum_j h[g,j]*mb[j]
#define WSEG 16
#define WBK 128
__global__ __launch_bounds__(256) void k_W(const float* __restrict__ out,
                                           const float* __restrict__ mwT,
                                           const float* __restrict__ mb,
                                           float* __restrict__ W,
                                           float* __restrict__ bsum) {
    __shared__ float smw[WBK][F_DIM];   // 64 KB
    __shared__ float shl[WSEG][WBK];    // 8 KB
    int g0 = blockIdx.x * WSEG;
    int t = threadIdx.x;
    int f = t & 127, sh = t >> 7;
    float acc[8] = {};
    for (int k0 = 0; k0 < H_DIM; k0 += WBK) {
        for (int i = t; i < WBK * 32; i += 256) {
            int r = i >> 5, c4 = (i & 31) << 2;
            *reinterpret_cast<float4*>(&smw[r][c4]) =
                *reinterpret_cast<const float4*>(&mwT[(size_t)(k0 + r) * F_DIM + c4]);
        }
        for (int i = t; i < WSEG * WBK / 4; i += 256) {
            int s = i >> 5, c4 = (i & 31) << 2;
            *reinterpret_cast<float4*>(&shl[s][c4]) =
                *reinterpret_cast<const float4*>(&out[(size_t)(g0 + s) * 1024 + k0 + c4]);
        }
        __syncthreads();
        for (int kk = 0; kk < WBK; ++kk) {
            float w = smw[kk][f];
#pragma unroll
            for (int s = 0; s < 8; ++s)
                acc[s] = fmaf(shl[sh + 2 * s][kk], w, acc[s]);
        }
        __syncthreads();
    }
#pragma unroll
    for (int s = 0; s < 8; ++s)
        W[(size_t)(g0 + sh + 2 * s) * F_DIM + f] = acc[s];
    int wv = t >> 6, lane = t & 63;
    for (int si = 0; si < 4; ++si) {
        int g = g0 + wv + si * 4;
        float b = 0.f;
        for (int j = lane; j < H_DIM; j += 64)
            b = fmaf(out[(size_t)g * 1024 + j], mb[j], b);
#pragma unroll
        for (int off = 32; off >= 1; off >>= 1) b += __shfl_xor(b, off);
        if (lane == 0) bsum[g] = b;
    }
}

// per-segment attn: 128 threads (2 waves) per segment
__global__ __launch_bounds__(128) void k_attn(const float* __restrict__ feats,
                                              const float* __restrict__ wts,
                                              const float* __restrict__ W,
                                              const float* __restrict__ bsum,
                                              float* __restrict__ fsum) {
    int g = blockIdx.x;
    int t = threadIdx.x;           // 0..127
    __shared__ float fl[SEG_SZ * 129];
    __shared__ float Wl[F_DIM];
    __shared__ float ep[2][SEG_SZ];
    __shared__ float al[SEG_SZ];
    const float4* f4 = reinterpret_cast<const float4*>(feats + (size_t)g * SEG_SZ * F_DIM);
    for (int i = t; i < SEG_SZ * F_DIM / 4; i += 128) {
        float4 v = f4[i];
        int n = i >> 5;
        int f = (i & 31) << 2;
        float* p = &fl[n * 129 + f];
        p[0] = v.x; p[1] = v.y; p[2] = v.z; p[3] = v.w;
    }
    Wl[t] = W[g * F_DIM + t];
    __syncthreads();
    int row = t & 63, half = t >> 6;
    const float* fr = &fl[row * 129 + half * 64];
    const float* wr = &Wl[half * 64];
    float e = 0.f;
#pragma unroll
    for (int f = 0; f < 64; ++f) e = fmaf(fr[f], wr[f], e);
    ep[half][row] = e;
    __syncthreads();
    if (t < 64) {
        float ee = ep[0][t] + ep[1][t] + bsum[g];
        float mx = ee;
#pragma unroll
        for (int off = 32; off >= 1; off >>= 1) mx = fmaxf(mx, __shfl_xor(mx, off));
        float ex = expf(ee - mx) * wts[g * SEG_SZ + t];
        float s = ex;
#pragma unroll
        for (int off = 32; off >= 1; off >>= 1) s += __shfl_xor(s, off);
        al[t] = ex / s;
    }
    __syncthreads();
    float a0 = 0.f;
#pragma unroll
    for (int n = 0; n < SEG_SZ; ++n)
        a0 = fmaf(al[n], fl[n * 129 + t], a0);
    fsum[g * F_DIM + t] = a0;
}

// r[g] = fsum[g] @ mw + mb -> out[:, H:2H] and qsb bf16
#define RGB 8
__global__ __launch_bounds__(512) void k_r(const float* __restrict__ fsum,
                                           const float* __restrict__ mw,
                                           const float* __restrict__ mb,
                                           float* __restrict__ out,
                                           u16* __restrict__ qsb) {
    int g0 = blockIdx.x * RGB;
    int tid = threadIdx.x;
    __shared__ float fs[RGB][F_DIM];
    for (int i = tid; i < RGB * F_DIM; i += 512)
        fs[i >> 7][i & 127] = fsum[g0 * F_DIM + i];
    __syncthreads();
    float acc[RGB] = {};
    for (int f = 0; f < F_DIM; ++f) {
        float w = mw[f * H_DIM + tid];
#pragma unroll
        for (int s = 0; s < RGB; ++s) acc[s] = fmaf(fs[s][f], w, acc[s]);
    }
    float bias = mb[tid];
#pragma unroll
    for (int s = 0; s < RGB; ++s) {
        float v = acc[s] + bias;
        out[(size_t)(g0 + s) * 1024 + H_DIM + tid] = v;
        qsb[(size_t)(g0 + s) * 1024 + H_DIM + tid] = f2bf(v);
    }
}

extern "C" void kernel_launch(void* const* d_in, const int* in_sizes, int n_in,
                              void* d_out, int out_size, void* d_ws, size_t ws_size,
                              hipStream_t stream) {
    const float* feats = (const float*)d_in[0];
    const float* wts   = (const float*)d_in[1];
    // d_in[2] = index: structurally n/64 (sorted, 64 nodes/segment) — not needed
    const float* mw    = (const float*)d_in[3];
    const float* mb    = (const float*)d_in[4];
    const float* rk    = (const float*)d_in[5];
    const float* rb    = (const float*)d_in[6];
    float* out = (float*)d_out;

    float* c    = (float*)d_ws;                       // G*H    = 2M floats
    float* W    = c + (size_t)G_SEG * H_DIM;          // G*F    = 512K
    float* bs   = W + (size_t)G_SEG * F_DIM;          // G
    float* fsum = bs + G_SEG;                         // G*F    = 512K
    float* mwT  = fsum + (size_t)G_SEG * F_DIM;       // H*F    = 64K
    u16*   qsb  = (u16*)(mwT + H_DIM * F_DIM);        // G*2H bf16 = 8 MB
    u16*   btg  = qsb + (size_t)G_SEG * KDIM;         // N*K bf16  = 4 MB

    k_transpose<<<(F_DIM * H_DIM + 255) / 256, 256, 0, stream>>>(mw, mwT);
    k_bt<<<dim3(NDIM / 64, KDIM / 64), 256, 0, stream>>>(rk, btg);

    for (int t = 0; t < 3; ++t) {
        if (t > 0) {
            k_gemm_gates<<<dim3(H_DIM / 32, G_SEG / GBM), 256, 0, stream>>>(qsb, btg, rb, c, out, qsb);
        } else {
            k_gates0<<<(G_SEG * H_DIM) / 256, 256, 0, stream>>>(rb, c, out, qsb);
        }
        k_W<<<G_SEG / WSEG, 256, 0, stream>>>(out, mwT, mb, W, bs);
        k_attn<<<G_SEG, 128, 0, stream>>>(feats, wts, W, bs, fsum);
        k_r<<<G_SEG / RGB, 512, 0, stream>>>(fsum, mw, mb, out, qsb);
    }
}